// Round 16
// baseline (193.346 us; speedup 1.0000x reference)
//
#include <hip/hip_runtime.h>
#include <hip/hip_bf16.h>
#include <stdint.h>

// TripleAttention on MI355X (gfx950).
// B=1, N=2048, C=1024, H=16, hd=64.
//
// Accuracy strategy: scores s = (q1.k1)*(q2.k2) have row-max ~2500; softmax
// needs ~1e-5 RELATIVE score accuracy. bf16 MFMA alone is 2^-9 -> fail.
// => split-bf16 (hi+lo) 3-term MFMA for q1/q2/k1/k2 projections and both
//    Gram matrices (fp32-class accuracy at 1/3 bf16 rate).
// v / PV / LN / out-proj are insensitive -> plain bf16 MFMA.
//
// R16: k_proj rebuilt as BK=32 DOUBLE-BUFFERED (m97 recipe: stage next tile
// before computing current; vmcnt(0)+barrier after compute -> drain hidden).
// R15's k_proj was single-buffered: full load latency exposed every K-step.
// Packed LDS layout (2 rows / 128B LDS row) + chunk XOR swizzle = 2-way
// banks (free), linear gld16 dest + inverse-swizzled global source.
// k_attn = R13 exact (87.5us, best of 9 variants). k_ogemm BM=64.

#define N_SEQ 2048
#define CDIM  1024
#define NHEAD 16
#define HDIM  64

typedef __attribute__((ext_vector_type(8))) short bfrag;   // 8 bf16 (4 VGPR)
typedef __attribute__((ext_vector_type(4))) float f4;      // 16x16 acc
typedef __attribute__((ext_vector_type(16))) float f16v;   // 32x32 acc
typedef unsigned short u16;

#define MFMA16(a, b, c) __builtin_amdgcn_mfma_f32_16x16x32_bf16((a), (b), (c), 0, 0, 0)
#define MFMA32(a, b, c) __builtin_amdgcn_mfma_f32_32x32x16_bf16((a), (b), (c), 0, 0, 0)

__device__ __forceinline__ float bf2f(u16 u) {
  union { unsigned int i; float f; } c; c.i = ((unsigned int)u) << 16; return c.f;
}
__device__ __forceinline__ u16 f2bf(float f) {  // RNE
  union { float f; unsigned int i; } c; c.f = f;
  unsigned int i = c.i;
  return (u16)((i + 0x7FFFu + ((i >> 16) & 1u)) >> 16);
}
__device__ __forceinline__ unsigned int pk2(float lo, float hi) {  // bf16x2 RNE pack
  __hip_bfloat162 b = __float22bfloat162_rn(make_float2(lo, hi));
  unsigned int u;
  __builtin_memcpy(&u, &b, 4);
  return u;
}

__device__ __forceinline__ void gld16(const void* g, void* lds) {
  __builtin_amdgcn_global_load_lds(
      (const __attribute__((address_space(1))) void*)g,
      (__attribute__((address_space(3))) void*)lds, 16, 0, 0);
}

// ----- fused prep: z<6 = transpose+split weight wz; z>=6 = split x slice -----
__global__ __launch_bounds__(256) void k_prep(
    const float* __restrict__ W0, const float* __restrict__ W1,
    const float* __restrict__ W2, const float* __restrict__ W3,
    const float* __restrict__ W4, const float* __restrict__ W5,
    const float* __restrict__ x,
    u16* __restrict__ wth, u16* __restrict__ wtl,
    u16* __restrict__ xh, u16* __restrict__ xl) {
  int wz = blockIdx.z;
  int t = threadIdx.x;
  if (wz >= 6) {
    int blk = (wz - 6) * 256 + blockIdx.y * 16 + blockIdx.x;
    int i = blk * 1024 + t * 4;
    float4 v = *(const float4*)(x + i);
    float vv[4] = {v.x, v.y, v.z, v.w};
    ushort4 h, l;
    u16 hh[4], ll[4];
#pragma unroll
    for (int j = 0; j < 4; j++) {
      hh[j] = f2bf(vv[j]);
      ll[j] = f2bf(vv[j] - bf2f(hh[j]));
    }
    h.x = hh[0]; h.y = hh[1]; h.z = hh[2]; h.w = hh[3];
    l.x = ll[0]; l.y = ll[1]; l.z = ll[2]; l.w = ll[3];
    *(ushort4*)(xh + i) = h;
    *(ushort4*)(xl + i) = l;
    return;
  }
  __shared__ float tile[64][65];
  const float* W = wz == 0 ? W0 : wz == 1 ? W1 : wz == 2 ? W2 : wz == 3 ? W3 : wz == 4 ? W4 : W5;
  int kb = blockIdx.x * 64, nb = blockIdx.y * 64;
  int r0 = t >> 4, c0 = (t & 15) * 4;
#pragma unroll
  for (int i = 0; i < 4; i++) {
    int r = r0 + i * 16;
    float4 v = *(const float4*)(W + (size_t)(kb + r) * CDIM + nb + c0);
    tile[r][c0 + 0] = v.x; tile[r][c0 + 1] = v.y; tile[r][c0 + 2] = v.z; tile[r][c0 + 3] = v.w;
  }
  __syncthreads();
#pragma unroll
  for (int i = 0; i < 4; i++) {
    int wn = (t >> 4) + i * 16;   // n within tile
    int wk = (t & 15) * 4;        // k within tile
    ushort4 h, l;
    u16 hh[4], ll[4];
#pragma unroll
    for (int j = 0; j < 4; j++) {
      float v = tile[wk + j][wn];
      hh[j] = f2bf(v);
      ll[j] = f2bf(v - bf2f(hh[j]));
    }
    h.x = hh[0]; h.y = hh[1]; h.z = hh[2]; h.w = hh[3];
    l.x = ll[0]; l.y = ll[1]; l.z = ll[2]; l.w = ll[3];
    size_t off = ((size_t)wz * CDIM + nb + wn) * CDIM + kb + wk;
    *(ushort4*)(wth + off) = h;
    if (wz < 4) *(ushort4*)(wtl + off) = l;
  }
}

// ------------- fused 5-projection GEMM: P_w = x + x@W_w + b_w -------------
// grid (40,16): w = bx/8, 128x128 tile, BK=32, DOUBLE-BUFFERED (m97 recipe).
// LDS: 2 bufs x 4 tensors x 8KB = 64KB -> 2 blocks/CU. Packed layout:
// logical (r,c4) -> LDS row R=r>>1, chunk s=((r&1)*4+c4)^(R&7) (bijective,
// 2-way banks on b128 reads). gld16 dest linear; global source inv-swizzled.
__global__ __launch_bounds__(256, 2) void k_proj(
    const u16* __restrict__ xh, const u16* __restrict__ xl,
    const u16* __restrict__ wth, const u16* __restrict__ wtl,
    const float* __restrict__ x,
    const float* __restrict__ b0, const float* __restrict__ b1,
    const float* __restrict__ b2, const float* __restrict__ b3,
    const float* __restrict__ b4,
    u16* __restrict__ qh, u16* __restrict__ ql, u16* __restrict__ vT) {
  __shared__ u16 sbuf[2][4][64 * 64];  // [buf][tensor Ah,Al,Bh,Bl][64 LDS rows x 64 u16]
  int t = threadIdx.x;
  int w = blockIdx.x >> 3;
  int n0 = (blockIdx.x & 7) * 128;
  int m0 = blockIdx.y * 128;
  int lane = t & 63, wid = t >> 6;
  int wm = (wid >> 1) * 64, wn = (wid & 1) * 64;
  int lr = lane & 15, lg = lane >> 4;
  const bool split = (w < 4);

  f4 acc[4][4];
#pragma unroll
  for (int i = 0; i < 4; i++)
#pragma unroll
    for (int j = 0; j < 4; j++) acc[i][j] = (f4)0.0f;

  const u16* wbh = wth + (size_t)w * CDIM * CDIM;
  const u16* wbl = wtl + (size_t)w * CDIM * CDIM;

  // staging source coords for this thread (2 chunks per tensor per step)
  int rS[2], cS[2], qS[2];
#pragma unroll
  for (int p = 0; p < 2; p++) {
    int q_ = t + p * 256;          // chunk id 0..511
    int R_ = q_ >> 3, s_ = q_ & 7;
    int cp_ = s_ ^ (R_ & 7);
    rS[p] = 2 * R_ + (cp_ >> 2);   // logical row 0..127
    cS[p] = (cp_ & 3) * 8;         // u16 col 0..31
    qS[p] = q_ * 8;                // LDS u16 offset (linear)
  }

#define STAGEP(bi, kt)                                                        \
  {                                                                           \
    _Pragma("unroll") for (int p = 0; p < 2; p++) {                           \
      size_t ga_ = (size_t)(m0 + rS[p]) * CDIM + (kt) + cS[p];                \
      size_t gb_ = (size_t)(n0 + rS[p]) * CDIM + (kt) + cS[p];                \
      gld16(xh + ga_, &sbuf[bi][0][qS[p]]);                                   \
      gld16(wbh + gb_, &sbuf[bi][2][qS[p]]);                                  \
      if (split) {                                                            \
        gld16(xl + ga_, &sbuf[bi][1][qS[p]]);                                 \
        gld16(wbl + gb_, &sbuf[bi][3][qS[p]]);                                \
      }                                                                       \
    }                                                                         \
  }

  // fragment LDS offsets (u16): row r, chunk lg
  int offA[4], offB[4];
#pragma unroll
  for (int i = 0; i < 4; i++) {
    int ra = wm + i * 16 + lr;
    offA[i] = (ra >> 1) * 64 + (((((ra & 1) << 2) | lg) ^ ((ra >> 1) & 7)) * 8);
    int rb = wn + i * 16 + lr;
    offB[i] = (rb >> 1) * 64 + (((((rb & 1) << 2) | lg) ^ ((rb >> 1) & 7)) * 8);
  }

  STAGEP(0, 0);
  asm volatile("s_waitcnt vmcnt(0)" ::: "memory");
  __builtin_amdgcn_s_barrier();

#pragma unroll 1
  for (int it = 0; it < CDIM / 32; it++) {
    int cb = it & 1;
    if (it + 1 < CDIM / 32) STAGEP(cb ^ 1, (it + 1) * 32);

    bfrag afh[4], bvh[4];
#pragma unroll
    for (int mi = 0; mi < 4; mi++) afh[mi] = *(const bfrag*)(&sbuf[cb][0][offA[mi]]);
#pragma unroll
    for (int ni = 0; ni < 4; ni++) bvh[ni] = *(const bfrag*)(&sbuf[cb][2][offB[ni]]);
#pragma unroll
    for (int mi = 0; mi < 4; mi++)
#pragma unroll
      for (int ni = 0; ni < 4; ni++)
        acc[mi][ni] = MFMA16(afh[mi], bvh[ni], acc[mi][ni]);
    if (split) {
      bfrag afl[4], bvl[4];
#pragma unroll
      for (int mi = 0; mi < 4; mi++) afl[mi] = *(const bfrag*)(&sbuf[cb][1][offA[mi]]);
#pragma unroll
      for (int ni = 0; ni < 4; ni++) bvl[ni] = *(const bfrag*)(&sbuf[cb][3][offB[ni]]);
#pragma unroll
      for (int mi = 0; mi < 4; mi++)
#pragma unroll
        for (int ni = 0; ni < 4; ni++) {
          acc[mi][ni] = MFMA16(afh[mi], bvl[ni], acc[mi][ni]);
          acc[mi][ni] = MFMA16(afl[mi], bvh[ni], acc[mi][ni]);
        }
    }

    asm volatile("s_waitcnt vmcnt(0)" ::: "memory");
    __builtin_amdgcn_s_barrier();
  }
#undef STAGEP

  const float* bias = w == 0 ? b0 : w == 1 ? b1 : w == 2 ? b2 : w == 3 ? b3 : b4;
#pragma unroll
  for (int mi = 0; mi < 4; mi++) {
#pragma unroll
    for (int ni = 0; ni < 4; ni++) {
      int col = n0 + wn + ni * 16 + lr;       // 0..1023 within this weight
      int rowb = m0 + wm + mi * 16 + lg * 4;
      float vv[4];
#pragma unroll
      for (int r = 0; r < 4; r++)
        vv[r] = acc[mi][ni][r] + x[(size_t)(rowb + r) * CDIM + col] + bias[col];
      if (split) {
#pragma unroll
        for (int r = 0; r < 4; r++) {
          u16 h = f2bf(vv[r]);
          u16 l = f2bf(vv[r] - bf2f(h));
          qh[((size_t)w * N_SEQ + rowb + r) * CDIM + col] = h;
          ql[((size_t)w * N_SEQ + rowb + r) * CDIM + col] = l;
        }
      } else {
        ushort4 pv;
        pv.x = f2bf(vv[0]); pv.y = f2bf(vv[1]); pv.z = f2bf(vv[2]); pv.w = f2bf(vv[3]);
        *(ushort4*)(vT + (size_t)col * N_SEQ + rowb) = pv;
      }
    }
  }
}

// ---------------- flash attention: split-K x2, 32x32 MFMA, shfl P ----------------
// grid 512: khalf = bid>>8; inner 256 blocks XCD-swizzled. Block = 4 waves
// x 32 q = 128 q, one head. KVBLK=64, 64KB LDS dbuf. R7/R13 structure exact.
__global__ __launch_bounds__(256, 2) void k_attn(
    const u16* __restrict__ qkh, const u16* __restrict__ qkl,
    const u16* __restrict__ vT, u16* __restrict__ O0, u16* __restrict__ O1,
    float2* __restrict__ ml) {
  __shared__ u16 sbuf[2][32 * 512];  // [buf][chunk = tensor*8 + kh*4 + ks][1KB]
  int bid = blockIdx.x;
  int khalf = bid >> 8;
  int inner = bid & 255;
  int vb = (inner & 7) * 32 + (inner >> 3);   // bijective XCD swizzle
  int h = vb >> 4;
  int qb = (vb & 15) * 128;
  int t = threadIdx.x, lane = t & 63, wv = t >> 6;
  int l31 = lane & 31, hi5 = lane >> 5;
  const size_t NC = (size_t)N_SEQ * CDIM;
  const int hoff = h * HDIM;
  const int k0 = khalf * (N_SEQ / 2);
  u16* Op = khalf ? O1 : O0;

  // Q fragments (B operand; row = q = lane&31, elems = ks*16 + hi5*8)
  int qrow = qb + wv * 32 + l31;
  bfrag q1h[4], q1l[4], q2h[4], q2l[4];
#pragma unroll
  for (int ks = 0; ks < 4; ks++) {
    size_t off = (size_t)qrow * CDIM + hoff + ks * 16 + hi5 * 8;
    q1h[ks] = *(const bfrag*)(qkh + off);
    q1l[ks] = *(const bfrag*)(qkl + off);
    q2h[ks] = *(const bfrag*)(qkh + NC + off);
    q2l[ks] = *(const bfrag*)(qkl + NC + off);
  }

  // wave wv stages tensor wv of {k1h,k1l,k2h,k2l}
  const u16* kb = ((wv & 1) ? qkl : qkh) + (size_t)(2 + (wv >> 1)) * NC;

  float mrun = -1e30f, lrun = 0.f;
  f16v accO0 = (f16v)0.0f, accO1 = (f16v)0.0f;

#define STAGE(bi, kt)                                                          \
  {                                                                            \
    _Pragma("unroll") for (int i = 0; i < 8; i++) {                            \
      int kh_ = i >> 2, ksp_ = i & 3;                                          \
      gld16(kb + (size_t)((kt) + kh_ * 32 + l31) * CDIM + hoff + ksp_ * 16 +   \
                hi5 * 8,                                                       \
            sbuf[bi] + ((wv * 8 + i) << 9));                                   \
    }                                                                          \
  }

  STAGE(0, k0);
  asm volatile("s_waitcnt vmcnt(0)" ::: "memory");
  __builtin_amdgcn_s_barrier();

#pragma unroll 1
  for (int it = 0; it < N_SEQ / 2 / 64; it++) {
    int kt = k0 + it * 64;
    if (it + 1 < N_SEQ / 2 / 64) STAGE((it + 1) & 1, kt + 64);

    // hoist V loads: latency hides under QK^T
    bfrag vld[2][4];
#pragma unroll
    for (int kh = 0; kh < 2; kh++) {
      const u16* vb0 = vT + (size_t)(hoff + l31) * N_SEQ + kt + kh * 32 + hi5 * 8;
      const u16* vb1 = vT + (size_t)(hoff + 32 + l31) * N_SEQ + kt + kh * 32 + hi5 * 8;
      vld[kh][0] = *(const bfrag*)(vb0);
      vld[kh][1] = *(const bfrag*)(vb0 + 16);
      vld[kh][2] = *(const bfrag*)(vb1);
      vld[kh][3] = *(const bfrag*)(vb1 + 16);
    }

    const u16* sb = sbuf[it & 1];
    // QK^T: s1[kh] = (K1.Q1), s2[kh] = (K2.Q2), 3-term split each
    f16v s1[2], s2[2];
#pragma unroll
    for (int kh = 0; kh < 2; kh++) { s1[kh] = (f16v)0.0f; s2[kh] = (f16v)0.0f; }
#pragma unroll
    for (int kh = 0; kh < 2; kh++) {
#pragma unroll
      for (int ks = 0; ks < 4; ks++) {
        const u16* cb = sb + ((kh * 4 + ks) << 9) + lane * 8;
        bfrag k1h = *(const bfrag*)(cb);
        bfrag k1l = *(const bfrag*)(cb + (8 << 9));
        bfrag k2h = *(const bfrag*)(cb + (16 << 9));
        bfrag k2l = *(const bfrag*)(cb + (24 << 9));
        s1[kh] = MFMA32(k1h, q1h[ks], s1[kh]);
        s1[kh] = MFMA32(k1h, q1l[ks], s1[kh]);
        s1[kh] = MFMA32(k1l, q1h[ks], s1[kh]);
        s2[kh] = MFMA32(k2h, q2h[ks], s2[kh]);
        s2[kh] = MFMA32(k2h, q2l[ks], s2[kh]);
        s2[kh] = MFMA32(k2l, q2h[ks], s2[kh]);
      }
    }
    f16v p0 = s1[0] * s2[0];   // scores, k = kt + 0..31 (per-lane rows)
    f16v p1 = s1[1] * s2[1];   // scores, k = kt + 32..63

    // online softmax; lane pair (l, l^32) share q, keep identical state
    float pm = fmaxf(p0[0], p1[0]);
#pragma unroll
    for (int j = 1; j < 16; j++) pm = fmaxf(pm, fmaxf(p0[j], p1[j]));
    pm = fmaxf(pm, __shfl_xor(pm, 32, 64));
    if (__any(pm > mrun + 8.0f)) {   // defer-max (THR=8)
      float mnew = fmaxf(mrun, pm);
      float sc = __expf(mrun - mnew);
      lrun *= sc;
#pragma unroll
      for (int j = 0; j < 16; j++) { accO0[j] *= sc; accO1[j] *= sc; }
      mrun = mnew;
    }
    float rs = 0.f;
#pragma unroll
    for (int j = 0; j < 16; j++) { p0[j] = __expf(p0[j] - mrun); rs += p0[j]; }
#pragma unroll
    for (int j = 0; j < 16; j++) { p1[j] = __expf(p1[j] - mrun); rs += p1[j]; }
    rs += __shfl_xor(rs, 32, 64);
    lrun += rs;

    // pack p to bf16 dwords; partner exchange via shfl_xor(32) + hi5 select
    unsigned dw[16];
#pragma unroll
    for (int j = 0; j < 8; j++) dw[j] = pk2(p0[2 * j], p0[2 * j + 1]);
#pragma unroll
    for (int j = 0; j < 8; j++) dw[8 + j] = pk2(p1[2 * j], p1[2 * j + 1]);

#pragma unroll
    for (int kh = 0; kh < 2; kh++) {
      unsigned j0 = dw[kh * 8 + 0], j1 = dw[kh * 8 + 1], j2 = dw[kh * 8 + 2],
               j3 = dw[kh * 8 + 3], j4 = dw[kh * 8 + 4], j5 = dw[kh * 8 + 5],
               j6 = dw[kh * 8 + 6], j7 = dw[kh * 8 + 7];
      unsigned pj0 = __shfl_xor(j0, 32, 64), pj1 = __shfl_xor(j1, 32, 64);
      unsigned pj2 = __shfl_xor(j2, 32, 64), pj3 = __shfl_xor(j3, 32, 64);
      unsigned pj4 = __shfl_xor(j4, 32, 64), pj5 = __shfl_xor(j5, 32, 64);
      unsigned pj6 = __shfl_xor(j6, 32, 64), pj7 = __shfl_xor(j7, 32, 64);
      union { unsigned u[4]; bfrag b; } f0, f1;
      f0.u[0] = hi5 ? pj2 : j0;
      f0.u[1] = hi5 ? pj3 : j1;
      f0.u[2] = hi5 ? j2 : pj0;
      f0.u[3] = hi5 ? j3 : pj1;
      f1.u[0] = hi5 ? pj6 : j4;
      f1.u[1] = hi5 ? pj7 : j5;
      f1.u[2] = hi5 ? j6 : pj4;
      f1.u[3] = hi5 ? j7 : pj5;
      accO0 = MFMA32(vld[kh][0], f0.b, accO0);
      accO0 = MFMA32(vld[kh][1], f1.b, accO0);
      accO1 = MFMA32(vld[kh][2], f0.b, accO1);
      accO1 = MFMA32(vld[kh][3], f1.b, accO1);
    }

    asm volatile("s_waitcnt vmcnt(0)" ::: "memory");
    __builtin_amdgcn_s_barrier();
  }
#undef STAGE

  // store unnormalized accO as bf16 + (m,l); d = 32*half + q4*8 + hi5*4 + j
#pragma unroll
  for (int q4 = 0; q4 < 4; q4++) {
    ushort4 s0, s1v;
    s0.x = f2bf(accO0[q4 * 4 + 0]); s0.y = f2bf(accO0[q4 * 4 + 1]);
    s0.z = f2bf(accO0[q4 * 4 + 2]); s0.w = f2bf(accO0[q4 * 4 + 3]);
    s1v.x = f2bf(accO1[q4 * 4 + 0]); s1v.y = f2bf(accO1[q4 * 4 + 1]);
    s1v.z = f2bf(accO1[q4 * 4 + 2]); s1v.w = f2bf(accO1[q4 * 4 + 3]);
    *(ushort4*)(Op + (size_t)qrow * CDIM + hoff + q4 * 8 + hi5 * 4) = s0;
    *(ushort4*)(Op + (size_t)qrow * CDIM + hoff + 32 + q4 * 8 + hi5 * 4) = s1v;
  }
  if (!hi5) ml[(size_t)(khalf * NHEAD + h) * N_SEQ + qrow] = make_float2(mrun, lrun);
}

// ---------------- combine split-K halves + LayerNorm (one row/block) ----------------
__global__ __launch_bounds__(256) void k_cln(
    const u16* __restrict__ O0, const u16* __restrict__ O1,
    const float2* __restrict__ ml, const float* __restrict__ g,
    const float* __restrict__ b, u16* __restrict__ oln) {
  __shared__ float rsm[4], rs2m[4];
  int row = blockIdx.x, t = threadIdx.x;
  int h = t >> 4;  // c = t*4, head = c/64
  float2 a = ml[(size_t)h * N_SEQ + row];
  float2 bb = ml[(size_t)(NHEAD + h) * N_SEQ + row];
  float M = fmaxf(a.x, bb.x);
  float w0 = __expf(a.x - M), w1 = __expf(bb.x - M);
  float invL = 1.0f / (w0 * a.y + w1 * bb.y);
  ushort4 u0 = *(const ushort4*)(O0 + (size_t)row * CDIM + t * 4);
  ushort4 u1 = *(const ushort4*)(O1 + (size_t)row * CDIM + t * 4);
  float vals[4];
  vals[0] = (w0 * bf2f(u0.x) + w1 * bf2f(u1.x)) * invL;
  vals[1] = (w0 * bf2f(u0.y) + w1 * bf2f(u1.y)) * invL;
  vals[2] = (w0 * bf2f(u0.z) + w1 * bf2f(u1.z)) * invL;
  vals[3] = (w0 * bf2f(u0.w) + w1 * bf2f(u1.w)) * invL;
  float s = vals[0] + vals[1] + vals[2] + vals[3];
  float s2 = vals[0] * vals[0] + vals[1] * vals[1] + vals[2] * vals[2] + vals[3] * vals[3];
#pragma unroll
  for (int d = 1; d < 64; d <<= 1) {
    s += __shfl_xor(s, d, 64);
    s2 += __shfl_xor(s2, d, 64);
  }
  int wv = t >> 6;
  if ((t & 63) == 0) { rsm[wv] = s; rs2m[wv] = s2; }
  __syncthreads();
  s = rsm[0] + rsm[1] + rsm[2] + rsm[3];
  s2 = rs2m[0] + rs2m[1] + rs2m[2] + rs2m[3];
  float mu = s * (1.0f / CDIM);
  float var = s2 * (1.0f / CDIM) - mu * mu;
  float inv = rsqrtf(var + 1e-5f);
  ushort4 r4;
  u16 rr[4];
#pragma unroll
  for (int j = 0; j < 4; j++) {
    int col = t * 4 + j;
    rr[j] = f2bf((vals[j] - mu) * inv * g[col] + b[col]);
  }
  r4.x = rr[0]; r4.y = rr[1]; r4.z = rr[2]; r4.w = rr[3];
  *(ushort4*)(oln + (size_t)row * CDIM + t * 4) = r4;
}

// ---------------- out = oln @ W_out + b_out (plain bf16, BM=64) ----------------
// grid (8,32) = 256 blocks (full CU coverage). Tile 64x128, LDS 24KB.
__global__ __launch_bounds__(256, 2) void k_ogemm(
    const u16* __restrict__ A, const u16* __restrict__ Bw,
    const float* __restrict__ bias, float* __restrict__ out) {
  __shared__ u16 sA[64 * 64];
  __shared__ u16 sB[128 * 64];
  int t = threadIdx.x;
  int n0 = blockIdx.x * 128, m0 = blockIdx.y * 64;
  int lane = t & 63, wid = t >> 6;
  int wm = (wid >> 1) * 32, wn = (wid & 1) * 64;
  int lr = lane & 15, lg = lane >> 4;
  f4 acc[2][4];
#pragma unroll
  for (int i = 0; i < 2; i++)
#pragma unroll
    for (int j = 0; j < 4; j++) acc[i][j] = (f4)0.0f;
  int srow = t >> 3, scol = (t & 7) * 8, soff = srow * 64 + scol;
  for (int kt = 0; kt < CDIM; kt += 64) {
#pragma unroll
    for (int c = 0; c < 2; c++)
      gld16(A + (size_t)(m0 + srow + c * 32) * CDIM + kt + scol, (u16*)sA + soff + c * 2048);
#pragma unroll
    for (int c = 0; c < 4; c++)
      gld16(Bw + (size_t)(n0 + srow + c * 32) * CDIM + kt + scol, (u16*)sB + soff + c * 2048);
    __syncthreads();
#pragma unroll
    for (int kk = 0; kk < 2; kk++) {
      bfrag af[2], bv[4];
#pragma unroll
      for (int mi = 0; mi < 2; mi++)
        af[mi] = *(const bfrag*)(sA + (wm + mi * 16 + lr) * 64 + kk * 32 + lg * 8);
#pragma unroll
      for (int ni = 0; ni < 4; ni++)
        bv[ni] = *(const bfrag*)(sB + (wn + ni * 16 + lr) * 64 + kk * 32 + lg * 8);
#pragma unroll
      for (int mi = 0; mi < 2; mi++)
#pragma unroll
        for (int ni = 0; ni < 4; ni++)
          acc[mi][ni] = MFMA16(af[mi], bv[ni], acc[mi][ni]);
    }
    __syncthreads();
  }
#pragma unroll
  for (int mi = 0; mi < 2; mi++) {
#pragma unroll
    for (int ni = 0; ni < 4; ni++) {
      int col = n0 + wn + ni * 16 + lr;
      int rowb = m0 + wm + mi * 16 + lg * 4;
#pragma unroll
      for (int r = 0; r < 4; r++)
        out[(size_t)(rowb + r) * CDIM + col] = acc[mi][ni][r] + bias[col];
    }
  }
}

extern "C" void kernel_launch(void* const* d_in, const int* in_sizes, int n_in,
                              void* d_out, int out_size, void* d_ws, size_t ws_size,
                              hipStream_t stream) {
  const float* x   = (const float*)d_in[0];
  const float* Wq1 = (const float*)d_in[1];  const float* bq1 = (const float*)d_in[2];
  const float* Wq2 = (const float*)d_in[3];  const float* bq2 = (const float*)d_in[4];
  const float* Wk1 = (const float*)d_in[5];  const float* bk1 = (const float*)d_in[6];
  const float* Wk2 = (const float*)d_in[7];  const float* bk2 = (const float*)d_in[8];
  const float* Wv  = (const float*)d_in[9];  const float* bv  = (const float*)d_in[10];
  const float* Wo  = (const float*)d_in[11]; const float* bo  = (const float*)d_in[12];
  const float* lng = (const float*)d_in[13]; const float* lnb = (const float*)d_in[14];

  char* w = (char*)d_ws;  // 64 MiB total; aliases reuse regions dead at use time
  u16* xh  = (u16*)(w + (0ull << 20));    // 4 MiB   (dead after proj)
  u16* xl  = (u16*)(w + (4ull << 20));    // 4 MiB   (dead after proj)
  u16* wth = (u16*)(w + (8ull << 20));    // 12 MiB  [6][C][C] (W_out needed at end)
  u16* wtl = (u16*)(w + (20ull << 20));   // 8 MiB   [4][C][C] (dead after proj)
  u16* qsh = (u16*)(w + (28ull << 20));   // 16 MiB  [4][N][C] q1,q2,k1,k2 hi
  u16* qsl = (u16*)(w + (44ull << 20));   // 16 MiB  lo
  u16* vT  = (u16*)(w + (60ull << 20));   // 4 MiB   [C][N]
  u16* O0  = (u16*)(w + (0ull << 20));    // 4 MiB bf16 partial, aliases xh
  u16* O1  = (u16*)(w + (4ull << 20));    // 4 MiB bf16 partial, aliases xl
  float2* ml = (float2*)(w + (20ull << 20));  // 0.5 MiB [2][H][N], aliases wtl head
  u16* oln = (u16*)(w + (24ull << 20));   // 4 MiB, aliases wtl tail

  k_prep<<<dim3(16, 16, 14), 256, 0, stream>>>(Wq1, Wq2, Wk1, Wk2, Wv, Wo, x,
                                               wth, wtl, xh, xl);
  k_proj<<<dim3(40, 16), 256, 0, stream>>>(xh, xl, wth, wtl, x,
                                           bq1, bq2, bk1, bk2, bv, qsh, qsl, vT);
  k_attn<<<512, 256, 0, stream>>>(qsh, qsl, vT, O0, O1, ml);
  k_cln<<<2048, 256, 0, stream>>>(O0, O1, ml, lng, lnb, oln);
  k_ogemm<<<dim3(8, 32), 256, 0, stream>>>(oln, wth + 5ull * CDIM * CDIM, bo, (float*)d_out);
}

// Round 17
// 186.151 us; speedup vs baseline: 1.0387x; 1.0387x over previous
//
#include <hip/hip_runtime.h>
#include <hip/hip_bf16.h>
#include <stdint.h>

// TripleAttention on MI355X (gfx950).
// B=1, N=2048, C=1024, H=16, hd=64.
//
// Accuracy strategy: scores s = (q1.k1)*(q2.k2) have row-max ~2500; softmax
// needs ~1e-5 RELATIVE score accuracy. bf16 MFMA alone is 2^-9 -> fail.
// => split-bf16 (hi+lo) 3-term MFMA for q1/q2/k1/k2 projections and both
//    Gram matrices (fp32-class accuracy at 1/3 bf16 rate).
// v / PV / LN / out-proj are insensitive -> plain bf16 MFMA.
//
// R17 = R15 exact (best measured: 186.2us). R16's k_proj BK=32 double-buffer
// regressed (+7us: vmcnt(0) drains at every barrier regardless -> doubling
// barrier events while halving MFMA/barrier loses; BK=64 single-buffer
// amortizes best). k_attn = R13 (87.5us, best of 9 structural variants).
// k_ogemm BM=64 (full CU coverage). prep fused (weights + x split).

#define N_SEQ 2048
#define CDIM  1024
#define NHEAD 16
#define HDIM  64

typedef __attribute__((ext_vector_type(8))) short bfrag;   // 8 bf16 (4 VGPR)
typedef __attribute__((ext_vector_type(4))) float f4;      // 16x16 acc
typedef __attribute__((ext_vector_type(16))) float f16v;   // 32x32 acc
typedef unsigned short u16;

#define MFMA16(a, b, c) __builtin_amdgcn_mfma_f32_16x16x32_bf16((a), (b), (c), 0, 0, 0)
#define MFMA32(a, b, c) __builtin_amdgcn_mfma_f32_32x32x16_bf16((a), (b), (c), 0, 0, 0)

__device__ __forceinline__ float bf2f(u16 u) {
  union { unsigned int i; float f; } c; c.i = ((unsigned int)u) << 16; return c.f;
}
__device__ __forceinline__ u16 f2bf(float f) {  // RNE
  union { float f; unsigned int i; } c; c.f = f;
  unsigned int i = c.i;
  return (u16)((i + 0x7FFFu + ((i >> 16) & 1u)) >> 16);
}
__device__ __forceinline__ unsigned int pk2(float lo, float hi) {  // bf16x2 RNE pack
  __hip_bfloat162 b = __float22bfloat162_rn(make_float2(lo, hi));
  unsigned int u;
  __builtin_memcpy(&u, &b, 4);
  return u;
}

__device__ __forceinline__ void gld16(const void* g, void* lds) {
  __builtin_amdgcn_global_load_lds(
      (const __attribute__((address_space(1))) void*)g,
      (__attribute__((address_space(3))) void*)lds, 16, 0, 0);
}

// ----- fused prep: z<6 = transpose+split weight wz; z>=6 = split x slice -----
__global__ __launch_bounds__(256) void k_prep(
    const float* __restrict__ W0, const float* __restrict__ W1,
    const float* __restrict__ W2, const float* __restrict__ W3,
    const float* __restrict__ W4, const float* __restrict__ W5,
    const float* __restrict__ x,
    u16* __restrict__ wth, u16* __restrict__ wtl,
    u16* __restrict__ xh, u16* __restrict__ xl) {
  int wz = blockIdx.z;
  int t = threadIdx.x;
  if (wz >= 6) {
    // split x: slice (wz-6) of 8; block = (by*16+bx); 1024 floats per block
    int blk = (wz - 6) * 256 + blockIdx.y * 16 + blockIdx.x;
    int i = blk * 1024 + t * 4;
    float4 v = *(const float4*)(x + i);
    float vv[4] = {v.x, v.y, v.z, v.w};
    ushort4 h, l;
    u16 hh[4], ll[4];
#pragma unroll
    for (int j = 0; j < 4; j++) {
      hh[j] = f2bf(vv[j]);
      ll[j] = f2bf(vv[j] - bf2f(hh[j]));
    }
    h.x = hh[0]; h.y = hh[1]; h.z = hh[2]; h.w = hh[3];
    l.x = ll[0]; l.y = ll[1]; l.z = ll[2]; l.w = ll[3];
    *(ushort4*)(xh + i) = h;
    *(ushort4*)(xl + i) = l;
    return;
  }
  __shared__ float tile[64][65];
  const float* W = wz == 0 ? W0 : wz == 1 ? W1 : wz == 2 ? W2 : wz == 3 ? W3 : wz == 4 ? W4 : W5;
  int kb = blockIdx.x * 64, nb = blockIdx.y * 64;
  int r0 = t >> 4, c0 = (t & 15) * 4;
#pragma unroll
  for (int i = 0; i < 4; i++) {
    int r = r0 + i * 16;
    float4 v = *(const float4*)(W + (size_t)(kb + r) * CDIM + nb + c0);
    tile[r][c0 + 0] = v.x; tile[r][c0 + 1] = v.y; tile[r][c0 + 2] = v.z; tile[r][c0 + 3] = v.w;
  }
  __syncthreads();
#pragma unroll
  for (int i = 0; i < 4; i++) {
    int wn = (t >> 4) + i * 16;   // n within tile
    int wk = (t & 15) * 4;        // k within tile
    ushort4 h, l;
    u16 hh[4], ll[4];
#pragma unroll
    for (int j = 0; j < 4; j++) {
      float v = tile[wk + j][wn];
      hh[j] = f2bf(v);
      ll[j] = f2bf(v - bf2f(hh[j]));
    }
    h.x = hh[0]; h.y = hh[1]; h.z = hh[2]; h.w = hh[3];
    l.x = ll[0]; l.y = ll[1]; l.z = ll[2]; l.w = ll[3];
    size_t off = ((size_t)wz * CDIM + nb + wn) * CDIM + kb + wk;
    *(ushort4*)(wth + off) = h;
    if (wz < 4) *(ushort4*)(wtl + off) = l;
  }
}

// ------------- fused 5-projection GEMM: P_w = x + x@W_w + b_w -------------
// grid (40,16): w = bx/8, 128x128 tile. w<4: ONE K-loop staging {xh,xl,Wh,Wl},
// 96 MFMA per 64-K step (3-term split). w==4: {xh,Wh}, 32 MFMA/step.
// Both-sides XOR swizzle: linear LDS dest, inverse-swizzled global source,
// swizzled ds_read -> conflict-free b128 fragment reads.
__global__ __launch_bounds__(256, 2) void k_proj(
    const u16* __restrict__ xh, const u16* __restrict__ xl,
    const u16* __restrict__ wth, const u16* __restrict__ wtl,
    const float* __restrict__ x,
    const float* __restrict__ b0, const float* __restrict__ b1,
    const float* __restrict__ b2, const float* __restrict__ b3,
    const float* __restrict__ b4,
    u16* __restrict__ qh, u16* __restrict__ ql, u16* __restrict__ vT) {
  __shared__ u16 sAh[128 * 64];
  __shared__ u16 sAl[128 * 64];
  __shared__ u16 sBh[128 * 64];
  __shared__ u16 sBl[128 * 64];
  int t = threadIdx.x;
  int w = blockIdx.x >> 3;
  int n0 = (blockIdx.x & 7) * 128;
  int m0 = blockIdx.y * 128;
  int lane = t & 63, wid = t >> 6;
  int wm = (wid >> 1) * 64, wn = (wid & 1) * 64;
  int lr = lane & 15, lg = lane >> 4;
  const bool split = (w < 4);

  f4 acc[4][4];
#pragma unroll
  for (int i = 0; i < 4; i++)
#pragma unroll
    for (int j = 0; j < 4; j++) acc[i][j] = (f4)0.0f;

  const u16* wbh = wth + (size_t)w * CDIM * CDIM;
  const u16* wbl = wtl + (size_t)w * CDIM * CDIM;

  int srow = t >> 3;                                   // 0..31
  int scolsw = (((t & 7) ^ ((t >> 3) & 7)) * 8);       // inverse-swizzled src col
  int soff = srow * 64 + (t & 7) * 8;                  // linear LDS dest (u16)

  for (int kt = 0; kt < CDIM; kt += 64) {
#pragma unroll
    for (int c = 0; c < 4; c++) {
      gld16(xh + (size_t)(m0 + srow + c * 32) * CDIM + kt + scolsw, sAh + soff + c * 2048);
      gld16(wbh + (size_t)(n0 + srow + c * 32) * CDIM + kt + scolsw, sBh + soff + c * 2048);
      if (split) {
        gld16(xl + (size_t)(m0 + srow + c * 32) * CDIM + kt + scolsw, sAl + soff + c * 2048);
        gld16(wbl + (size_t)(n0 + srow + c * 32) * CDIM + kt + scolsw, sBl + soff + c * 2048);
      }
    }
    __syncthreads();
#pragma unroll
    for (int kk = 0; kk < 2; kk++) {
      int cc = (((kk * 4 + lg) ^ (lr & 7))) * 8;  // swizzled u16 col offset
      bfrag afh[4], bvh[4];
#pragma unroll
      for (int mi = 0; mi < 4; mi++)
        afh[mi] = *(const bfrag*)(sAh + (wm + mi * 16 + lr) * 64 + cc);
#pragma unroll
      for (int ni = 0; ni < 4; ni++)
        bvh[ni] = *(const bfrag*)(sBh + (wn + ni * 16 + lr) * 64 + cc);
#pragma unroll
      for (int mi = 0; mi < 4; mi++)
#pragma unroll
        for (int ni = 0; ni < 4; ni++)
          acc[mi][ni] = MFMA16(afh[mi], bvh[ni], acc[mi][ni]);
      if (split) {
        bfrag afl[4], bvl[4];
#pragma unroll
        for (int mi = 0; mi < 4; mi++)
          afl[mi] = *(const bfrag*)(sAl + (wm + mi * 16 + lr) * 64 + cc);
#pragma unroll
        for (int ni = 0; ni < 4; ni++)
          bvl[ni] = *(const bfrag*)(sBl + (wn + ni * 16 + lr) * 64 + cc);
#pragma unroll
        for (int mi = 0; mi < 4; mi++)
#pragma unroll
          for (int ni = 0; ni < 4; ni++) {
            acc[mi][ni] = MFMA16(afh[mi], bvl[ni], acc[mi][ni]);
            acc[mi][ni] = MFMA16(afl[mi], bvh[ni], acc[mi][ni]);
          }
      }
    }
    __syncthreads();
  }

  const float* bias = w == 0 ? b0 : w == 1 ? b1 : w == 2 ? b2 : w == 3 ? b3 : b4;
#pragma unroll
  for (int mi = 0; mi < 4; mi++) {
#pragma unroll
    for (int ni = 0; ni < 4; ni++) {
      int col = n0 + wn + ni * 16 + lr;       // 0..1023 within this weight
      int rowb = m0 + wm + mi * 16 + lg * 4;
      float vv[4];
#pragma unroll
      for (int r = 0; r < 4; r++)
        vv[r] = acc[mi][ni][r] + x[(size_t)(rowb + r) * CDIM + col] + bias[col];
      if (split) {
#pragma unroll
        for (int r = 0; r < 4; r++) {
          u16 h = f2bf(vv[r]);
          u16 l = f2bf(vv[r] - bf2f(h));
          qh[((size_t)w * N_SEQ + rowb + r) * CDIM + col] = h;
          ql[((size_t)w * N_SEQ + rowb + r) * CDIM + col] = l;
        }
      } else {
        ushort4 pv;
        pv.x = f2bf(vv[0]); pv.y = f2bf(vv[1]); pv.z = f2bf(vv[2]); pv.w = f2bf(vv[3]);
        *(ushort4*)(vT + (size_t)col * N_SEQ + rowb) = pv;
      }
    }
  }
}

// ---------------- flash attention: split-K x2, 32x32 MFMA, shfl P ----------------
// grid 512: khalf = bid>>8; inner 256 blocks XCD-swizzled. Block = 4 waves
// x 32 q = 128 q, one head. KVBLK=64, 64KB LDS dbuf. R7/R13 structure exact.
__global__ __launch_bounds__(256, 2) void k_attn(
    const u16* __restrict__ qkh, const u16* __restrict__ qkl,
    const u16* __restrict__ vT, u16* __restrict__ O0, u16* __restrict__ O1,
    float2* __restrict__ ml) {
  __shared__ u16 sbuf[2][32 * 512];  // [buf][chunk = tensor*8 + kh*4 + ks][1KB]
  int bid = blockIdx.x;
  int khalf = bid >> 8;
  int inner = bid & 255;
  int vb = (inner & 7) * 32 + (inner >> 3);   // bijective XCD swizzle
  int h = vb >> 4;
  int qb = (vb & 15) * 128;
  int t = threadIdx.x, lane = t & 63, wv = t >> 6;
  int l31 = lane & 31, hi5 = lane >> 5;
  const size_t NC = (size_t)N_SEQ * CDIM;
  const int hoff = h * HDIM;
  const int k0 = khalf * (N_SEQ / 2);
  u16* Op = khalf ? O1 : O0;

  // Q fragments (B operand; row = q = lane&31, elems = ks*16 + hi5*8)
  int qrow = qb + wv * 32 + l31;
  bfrag q1h[4], q1l[4], q2h[4], q2l[4];
#pragma unroll
  for (int ks = 0; ks < 4; ks++) {
    size_t off = (size_t)qrow * CDIM + hoff + ks * 16 + hi5 * 8;
    q1h[ks] = *(const bfrag*)(qkh + off);
    q1l[ks] = *(const bfrag*)(qkl + off);
    q2h[ks] = *(const bfrag*)(qkh + NC + off);
    q2l[ks] = *(const bfrag*)(qkl + NC + off);
  }

  // wave wv stages tensor wv of {k1h,k1l,k2h,k2l}
  const u16* kb = ((wv & 1) ? qkl : qkh) + (size_t)(2 + (wv >> 1)) * NC;

  float mrun = -1e30f, lrun = 0.f;
  f16v accO0 = (f16v)0.0f, accO1 = (f16v)0.0f;

#define STAGE(bi, kt)                                                          \
  {                                                                            \
    _Pragma("unroll") for (int i = 0; i < 8; i++) {                            \
      int kh_ = i >> 2, ksp_ = i & 3;                                          \
      gld16(kb + (size_t)((kt) + kh_ * 32 + l31) * CDIM + hoff + ksp_ * 16 +   \
                hi5 * 8,                                                       \
            sbuf[bi] + ((wv * 8 + i) << 9));                                   \
    }                                                                          \
  }

  STAGE(0, k0);
  asm volatile("s_waitcnt vmcnt(0)" ::: "memory");
  __builtin_amdgcn_s_barrier();

#pragma unroll 1
  for (int it = 0; it < N_SEQ / 2 / 64; it++) {
    int kt = k0 + it * 64;
    if (it + 1 < N_SEQ / 2 / 64) STAGE((it + 1) & 1, kt + 64);

    // hoist V loads: latency hides under QK^T
    bfrag vld[2][4];
#pragma unroll
    for (int kh = 0; kh < 2; kh++) {
      const u16* vb0 = vT + (size_t)(hoff + l31) * N_SEQ + kt + kh * 32 + hi5 * 8;
      const u16* vb1 = vT + (size_t)(hoff + 32 + l31) * N_SEQ + kt + kh * 32 + hi5 * 8;
      vld[kh][0] = *(const bfrag*)(vb0);
      vld[kh][1] = *(const bfrag*)(vb0 + 16);
      vld[kh][2] = *(const bfrag*)(vb1);
      vld[kh][3] = *(const bfrag*)(vb1 + 16);
    }

    const u16* sb = sbuf[it & 1];
    // QK^T: s1[kh] = (K1.Q1), s2[kh] = (K2.Q2), 3-term split each
    f16v s1[2], s2[2];
#pragma unroll
    for (int kh = 0; kh < 2; kh++) { s1[kh] = (f16v)0.0f; s2[kh] = (f16v)0.0f; }
#pragma unroll
    for (int kh = 0; kh < 2; kh++) {
#pragma unroll
      for (int ks = 0; ks < 4; ks++) {
        const u16* cb = sb + ((kh * 4 + ks) << 9) + lane * 8;
        bfrag k1h = *(const bfrag*)(cb);
        bfrag k1l = *(const bfrag*)(cb + (8 << 9));
        bfrag k2h = *(const bfrag*)(cb + (16 << 9));
        bfrag k2l = *(const bfrag*)(cb + (24 << 9));
        s1[kh] = MFMA32(k1h, q1h[ks], s1[kh]);
        s1[kh] = MFMA32(k1h, q1l[ks], s1[kh]);
        s1[kh] = MFMA32(k1l, q1h[ks], s1[kh]);
        s2[kh] = MFMA32(k2h, q2h[ks], s2[kh]);
        s2[kh] = MFMA32(k2h, q2l[ks], s2[kh]);
        s2[kh] = MFMA32(k2l, q2h[ks], s2[kh]);
      }
    }
    f16v p0 = s1[0] * s2[0];   // scores, k = kt + 0..31 (per-lane rows)
    f16v p1 = s1[1] * s2[1];   // scores, k = kt + 32..63

    // online softmax; lane pair (l, l^32) share q, keep identical state
    float pm = fmaxf(p0[0], p1[0]);
#pragma unroll
    for (int j = 1; j < 16; j++) pm = fmaxf(pm, fmaxf(p0[j], p1[j]));
    pm = fmaxf(pm, __shfl_xor(pm, 32, 64));
    if (__any(pm > mrun + 8.0f)) {   // defer-max (THR=8)
      float mnew = fmaxf(mrun, pm);
      float sc = __expf(mrun - mnew);
      lrun *= sc;
#pragma unroll
      for (int j = 0; j < 16; j++) { accO0[j] *= sc; accO1[j] *= sc; }
      mrun = mnew;
    }
    float rs = 0.f;
#pragma unroll
    for (int j = 0; j < 16; j++) { p0[j] = __expf(p0[j] - mrun); rs += p0[j]; }
#pragma unroll
    for (int j = 0; j < 16; j++) { p1[j] = __expf(p1[j] - mrun); rs += p1[j]; }
    rs += __shfl_xor(rs, 32, 64);
    lrun += rs;

    // pack p to bf16 dwords; partner exchange via shfl_xor(32) + hi5 select
    unsigned dw[16];
#pragma unroll
    for (int j = 0; j < 8; j++) dw[j] = pk2(p0[2 * j], p0[2 * j + 1]);
#pragma unroll
    for (int j = 0; j < 8; j++) dw[8 + j] = pk2(p1[2 * j], p1[2 * j + 1]);

#pragma unroll
    for (int kh = 0; kh < 2; kh++) {
      unsigned j0 = dw[kh * 8 + 0], j1 = dw[kh * 8 + 1], j2 = dw[kh * 8 + 2],
               j3 = dw[kh * 8 + 3], j4 = dw[kh * 8 + 4], j5 = dw[kh * 8 + 5],
               j6 = dw[kh * 8 + 6], j7 = dw[kh * 8 + 7];
      unsigned pj0 = __shfl_xor(j0, 32, 64), pj1 = __shfl_xor(j1, 32, 64);
      unsigned pj2 = __shfl_xor(j2, 32, 64), pj3 = __shfl_xor(j3, 32, 64);
      unsigned pj4 = __shfl_xor(j4, 32, 64), pj5 = __shfl_xor(j5, 32, 64);
      unsigned pj6 = __shfl_xor(j6, 32, 64), pj7 = __shfl_xor(j7, 32, 64);
      union { unsigned u[4]; bfrag b; } f0, f1;
      f0.u[0] = hi5 ? pj2 : j0;
      f0.u[1] = hi5 ? pj3 : j1;
      f0.u[2] = hi5 ? j2 : pj0;
      f0.u[3] = hi5 ? j3 : pj1;
      f1.u[0] = hi5 ? pj6 : j4;
      f1.u[1] = hi5 ? pj7 : j5;
      f1.u[2] = hi5 ? j6 : pj4;
      f1.u[3] = hi5 ? j7 : pj5;
      accO0 = MFMA32(vld[kh][0], f0.b, accO0);
      accO0 = MFMA32(vld[kh][1], f1.b, accO0);
      accO1 = MFMA32(vld[kh][2], f0.b, accO1);
      accO1 = MFMA32(vld[kh][3], f1.b, accO1);
    }

    asm volatile("s_waitcnt vmcnt(0)" ::: "memory");
    __builtin_amdgcn_s_barrier();
  }
#undef STAGE

  // store unnormalized accO as bf16 + (m,l); d = 32*half + q4*8 + hi5*4 + j
#pragma unroll
  for (int q4 = 0; q4 < 4; q4++) {
    ushort4 s0, s1v;
    s0.x = f2bf(accO0[q4 * 4 + 0]); s0.y = f2bf(accO0[q4 * 4 + 1]);
    s0.z = f2bf(accO0[q4 * 4 + 2]); s0.w = f2bf(accO0[q4 * 4 + 3]);
    s1v.x = f2bf(accO1[q4 * 4 + 0]); s1v.y = f2bf(accO1[q4 * 4 + 1]);
    s1v.z = f2bf(accO1[q4 * 4 + 2]); s1v.w = f2bf(accO1[q4 * 4 + 3]);
    *(ushort4*)(Op + (size_t)qrow * CDIM + hoff + q4 * 8 + hi5 * 4) = s0;
    *(ushort4*)(Op + (size_t)qrow * CDIM + hoff + 32 + q4 * 8 + hi5 * 4) = s1v;
  }
  if (!hi5) ml[(size_t)(khalf * NHEAD + h) * N_SEQ + qrow] = make_float2(mrun, lrun);
}

// ---------------- combine split-K halves + LayerNorm (one row/block) ----------------
__global__ __launch_bounds__(256) void k_cln(
    const u16* __restrict__ O0, const u16* __restrict__ O1,
    const float2* __restrict__ ml, const float* __restrict__ g,
    const float* __restrict__ b, u16* __restrict__ oln) {
  __shared__ float rsm[4], rs2m[4];
  int row = blockIdx.x, t = threadIdx.x;
  int h = t >> 4;  // c = t*4, head = c/64
  float2 a = ml[(size_t)h * N_SEQ + row];
  float2 bb = ml[(size_t)(NHEAD + h) * N_SEQ + row];
  float M = fmaxf(a.x, bb.x);
  float w0 = __expf(a.x - M), w1 = __expf(bb.x - M);
  float invL = 1.0f / (w0 * a.y + w1 * bb.y);
  ushort4 u0 = *(const ushort4*)(O0 + (size_t)row * CDIM + t * 4);
  ushort4 u1 = *(const ushort4*)(O1 + (size_t)row * CDIM + t * 4);
  float vals[4];
  vals[0] = (w0 * bf2f(u0.x) + w1 * bf2f(u1.x)) * invL;
  vals[1] = (w0 * bf2f(u0.y) + w1 * bf2f(u1.y)) * invL;
  vals[2] = (w0 * bf2f(u0.z) + w1 * bf2f(u1.z)) * invL;
  vals[3] = (w0 * bf2f(u0.w) + w1 * bf2f(u1.w)) * invL;
  float s = vals[0] + vals[1] + vals[2] + vals[3];
  float s2 = vals[0] * vals[0] + vals[1] * vals[1] + vals[2] * vals[2] + vals[3] * vals[3];
#pragma unroll
  for (int d = 1; d < 64; d <<= 1) {
    s += __shfl_xor(s, d, 64);
    s2 += __shfl_xor(s2, d, 64);
  }
  int wv = t >> 6;
  if ((t & 63) == 0) { rsm[wv] = s; rs2m[wv] = s2; }
  __syncthreads();
  s = rsm[0] + rsm[1] + rsm[2] + rsm[3];
  s2 = rs2m[0] + rs2m[1] + rs2m[2] + rs2m[3];
  float mu = s * (1.0f / CDIM);
  float var = s2 * (1.0f / CDIM) - mu * mu;
  float inv = rsqrtf(var + 1e-5f);
  ushort4 r4;
  u16 rr[4];
#pragma unroll
  for (int j = 0; j < 4; j++) {
    int col = t * 4 + j;
    rr[j] = f2bf((vals[j] - mu) * inv * g[col] + b[col]);
  }
  r4.x = rr[0]; r4.y = rr[1]; r4.z = rr[2]; r4.w = rr[3];
  *(ushort4*)(oln + (size_t)row * CDIM + t * 4) = r4;
}

// ---------------- out = oln @ W_out + b_out (plain bf16, BM=64) ----------------
// grid (8,32) = 256 blocks (full CU coverage). Tile 64x128, LDS 24KB.
__global__ __launch_bounds__(256, 2) void k_ogemm(
    const u16* __restrict__ A, const u16* __restrict__ Bw,
    const float* __restrict__ bias, float* __restrict__ out) {
  __shared__ u16 sA[64 * 64];
  __shared__ u16 sB[128 * 64];
  int t = threadIdx.x;
  int n0 = blockIdx.x * 128, m0 = blockIdx.y * 64;
  int lane = t & 63, wid = t >> 6;
  int wm = (wid >> 1) * 32, wn = (wid & 1) * 64;
  int lr = lane & 15, lg = lane >> 4;
  f4 acc[2][4];
#pragma unroll
  for (int i = 0; i < 2; i++)
#pragma unroll
    for (int j = 0; j < 4; j++) acc[i][j] = (f4)0.0f;
  int srow = t >> 3, scol = (t & 7) * 8, soff = srow * 64 + scol;
  for (int kt = 0; kt < CDIM; kt += 64) {
#pragma unroll
    for (int c = 0; c < 2; c++)
      gld16(A + (size_t)(m0 + srow + c * 32) * CDIM + kt + scol, (u16*)sA + soff + c * 2048);
#pragma unroll
    for (int c = 0; c < 4; c++)
      gld16(Bw + (size_t)(n0 + srow + c * 32) * CDIM + kt + scol, (u16*)sB + soff + c * 2048);
    __syncthreads();
#pragma unroll
    for (int kk = 0; kk < 2; kk++) {
      bfrag af[2], bv[4];
#pragma unroll
      for (int mi = 0; mi < 2; mi++)
        af[mi] = *(const bfrag*)(sA + (wm + mi * 16 + lr) * 64 + kk * 32 + lg * 8);
#pragma unroll
      for (int ni = 0; ni < 4; ni++)
        bv[ni] = *(const bfrag*)(sB + (wn + ni * 16 + lr) * 64 + kk * 32 + lg * 8);
#pragma unroll
      for (int mi = 0; mi < 2; mi++)
#pragma unroll
        for (int ni = 0; ni < 4; ni++)
          acc[mi][ni] = MFMA16(af[mi], bv[ni], acc[mi][ni]);
    }
    __syncthreads();
  }
#pragma unroll
  for (int mi = 0; mi < 2; mi++) {
#pragma unroll
    for (int ni = 0; ni < 4; ni++) {
      int col = n0 + wn + ni * 16 + lr;
      int rowb = m0 + wm + mi * 16 + lg * 4;
#pragma unroll
      for (int r = 0; r < 4; r++)
        out[(size_t)(rowb + r) * CDIM + col] = acc[mi][ni][r] + bias[col];
    }
  }
}

extern "C" void kernel_launch(void* const* d_in, const int* in_sizes, int n_in,
                              void* d_out, int out_size, void* d_ws, size_t ws_size,
                              hipStream_t stream) {
  const float* x   = (const float*)d_in[0];
  const float* Wq1 = (const float*)d_in[1];  const float* bq1 = (const float*)d_in[2];
  const float* Wq2 = (const float*)d_in[3];  const float* bq2 = (const float*)d_in[4];
  const float* Wk1 = (const float*)d_in[5];  const float* bk1 = (const float*)d_in[6];
  const float* Wk2 = (const float*)d_in[7];  const float* bk2 = (const float*)d_in[8];
  const float* Wv  = (const float*)d_in[9];  const float* bv  = (const float*)d_in[10];
  const float* Wo  = (const float*)d_in[11]; const float* bo  = (const float*)d_in[12];
  const float* lng = (const float*)d_in[13]; const float* lnb = (const float*)d_in[14];

  char* w = (char*)d_ws;  // 64 MiB total; aliases reuse regions dead at use time
  u16* xh  = (u16*)(w + (0ull << 20));    // 4 MiB   (dead after proj)
  u16* xl  = (u16*)(w + (4ull << 20));    // 4 MiB   (dead after proj)
  u16* wth = (u16*)(w + (8ull << 20));    // 12 MiB  [6][C][C] (W_out needed at end)
  u16* wtl = (u16*)(w + (20ull << 20));   // 8 MiB   [4][C][C] (dead after proj)
  u16* qsh = (u16*)(w + (28ull << 20));   // 16 MiB  [4][N][C] q1,q2,k1,k2 hi
  u16* qsl = (u16*)(w + (44ull << 20));   // 16 MiB  lo
  u16* vT  = (u16*)(w + (60ull << 20));   // 4 MiB   [C][N]
  u16* O0  = (u16*)(w + (0ull << 20));    // 4 MiB bf16 partial, aliases xh
  u16* O1  = (u16*)(w + (4ull << 20));    // 4 MiB bf16 partial, aliases xl
  float2* ml = (float2*)(w + (20ull << 20));  // 0.5 MiB [2][H][N], aliases wtl head
  u16* oln = (u16*)(w + (24ull << 20));   // 4 MiB, aliases wtl tail

  k_prep<<<dim3(16, 16, 14), 256, 0, stream>>>(Wq1, Wq2, Wk1, Wk2, Wv, Wo, x,
                                               wth, wtl, xh, xl);
  k_proj<<<dim3(40, 16), 256, 0, stream>>>(xh, xl, wth, wtl, x,
                                           bq1, bq2, bk1, bk2, bv, qsh, qsl, vT);
  k_attn<<<512, 256, 0, stream>>>(qsh, qsl, vT, O0, O1, ml);
  k_cln<<<2048, 256, 0, stream>>>(O0, O1, ml, lng, lnb, oln);
  k_ogemm<<<dim3(8, 32), 256, 0, stream>>>(oln, wth + 5ull * CDIM * CDIM, bo, (float*)d_out);
}